// Round 3
// baseline (434.693 us; speedup 1.0000x reference)
//
#include <hip/hip_runtime.h>
#include <stdint.h>

// Problem constants (fixed by reference)
#define T_TOK 32768   // B*S = 8*4096
#define DIN   256
#define DHID  512
#define DOUT  256
#define NEXP  64
#define TM    64      // tokens per expert-FFN block
#define MAXTILES (2 * T_TOK / TM + NEXP)   // 1088 upper bound on sum ceil(cnt/TM)
#define ROUTER_BLOCKS (T_TOK / 64)         // 512
#define PREP_BLOCKS   8192

typedef __attribute__((ext_vector_type(8))) short short8;   // 8 bf16 (4 VGPRs)
typedef __attribute__((ext_vector_type(4))) float f32x4;

// ---- workspace layout (bytes) ----  total ~34.6 MB
#define OFF_W1F   0u                       // 16 MiB bf16 fragment-ordered W1
#define OFF_W2F   16777216u                // 16 MiB bf16 fragment-ordered W2
#define OFF_BASE  33554432u
#define OFF_CNT   (OFF_BASE + 0u)          // 64 int
#define OFF_CUR   (OFF_BASE + 256u)        // 64 int
#define OFF_OFFS  (OFF_BASE + 512u)        // 65 int
#define OFF_TILE  (OFF_BASE + 1024u)       // 65 int (tile-count prefix)
#define OFF_TOPKE (OFF_BASE + 2048u)       // 2T int
#define OFF_TOPKG (OFF_TOPKE + 262144u)    // 2T float
#define OFF_PERM  (OFF_TOPKG + 262144u)    // 2T int
#define OFF_PGATE (OFF_PERM + 262144u)     // 2T float

__device__ __forceinline__ unsigned short f2bf(float f) {
    union { float f; unsigned u; } a; a.f = f;
    unsigned u = a.u;
    u += 0x7fffu + ((u >> 16) & 1u);   // RNE
    return (unsigned short)(u >> 16);
}
__device__ __forceinline__ unsigned pack2(float a, float b) {
    return (unsigned)f2bf(a) | ((unsigned)f2bf(b) << 16);
}

// ---------------------------------------------------------------------------
// Fused K1: blocks [0,512) = router (fp32 logits, top-2, softmax, count);
// blocks [512, 8704) = weight prep (fp32 -> bf16 MFMA B-fragment order).
// The two halves are independent; fusing overlaps prep's memory-bound work
// with the router's FMA-bound work and saves a dispatch.
// B-fragment order: per 16(N)x32(K) tile, lane l holds
// B[k=kt*32+(l>>4)*8+j][n=nt*16+(l&15)], 64 lanes * 16B contiguous.
__global__ __launch_bounds__(256) void router_prep(const float* __restrict__ x,
                                                   const float* __restrict__ Wr,
                                                   const float* __restrict__ br,
                                                   const float* __restrict__ W1,
                                                   const float* __restrict__ W2,
                                                   uint4* __restrict__ W1f,
                                                   uint4* __restrict__ W2f,
                                                   int* __restrict__ topk_e,
                                                   float* __restrict__ topk_g,
                                                   int* __restrict__ cnt) {
    __shared__ float xl[64][68];   // x chunk [tok][d], later logits [tok][e]
    __shared__ float wt[64][68];   // Wr transposed chunk [e][d]
    __shared__ int lcnt[NEXP];
    int tid = threadIdx.x;

    if (blockIdx.x >= ROUTER_BLOCKS) {
        // ---------------- weight prep ----------------
        int g = (blockIdx.x - ROUTER_BLOCKS) * 256 + tid;   // 0 .. 2*2^20-1
        int isW2 = g >> 20;
        int gg = g & ((1 << 20) - 1);
        int l = gg & 63;
        int t = gg >> 6;            // tile id over all experts
        int e = t >> 8;
        int rem = t & 255;
        int quad = l >> 4, lr = l & 15;
        float v[8];
        if (!isW2) {
            int nt = rem >> 3, kt = rem & 7;          // 32 n-tiles, 8 k-tiles
            int kb = kt * 32 + quad * 8;
            int n = nt * 16 + lr;
            const float* s = W1 + (size_t)e * DIN * DHID + n;
#pragma unroll
            for (int j = 0; j < 8; ++j) v[j] = s[(size_t)(kb + j) * DHID];
        } else {
            int nt = rem >> 4, kt = rem & 15;         // 16 n-tiles, 16 k-tiles
            int kb = kt * 32 + quad * 8;
            int n = nt * 16 + lr;
            const float* s = W2 + (size_t)e * DHID * DOUT + n;
#pragma unroll
            for (int j = 0; j < 8; ++j) v[j] = s[(size_t)(kb + j) * DOUT];
        }
        uint4 o;
        o.x = pack2(v[0], v[1]); o.y = pack2(v[2], v[3]);
        o.z = pack2(v[4], v[5]); o.w = pack2(v[6], v[7]);
        (isW2 ? W2f : W1f)[gg] = o;
        return;
    }

    // ---------------- router ----------------
    if (tid < NEXP) lcnt[tid] = 0;
    int a = tid >> 4;        // expert group base
    int bcol = tid & 15;     // token group base
    int tok0 = blockIdx.x * 64;
    float c[4][4];
#pragma unroll
    for (int i = 0; i < 4; ++i)
#pragma unroll
        for (int j = 0; j < 4; ++j) c[i][j] = 0.0f;

    for (int chunk = 0; chunk < 4; ++chunk) {
        int d0 = chunk * 64;
        {   // stage x[tok0..tok0+63][d0..d0+63]
            int tok = tid >> 2, off = (tid & 3) * 16;
            const float4* s = (const float4*)(x + (size_t)(tok0 + tok) * DIN + d0 + off);
            float4* d = (float4*)&xl[tok][off];
#pragma unroll
            for (int i = 0; i < 4; ++i) d[i] = s[i];
        }
        {   // stage Wr chunk transposed: wt[e][dd] = Wr[d0+dd][e]
            int dd = tid >> 2, ecol = (tid & 3) * 16;
            const float* s = Wr + (size_t)(d0 + dd) * NEXP + ecol;
#pragma unroll
            for (int j = 0; j < 16; ++j) wt[ecol + j][dd] = s[j];
        }
        __syncthreads();
#pragma unroll 4
        for (int d = 0; d < 64; d += 4) {
            float4 xv[4], wv[4];
#pragma unroll
            for (int i = 0; i < 4; ++i) xv[i] = *(const float4*)&xl[bcol + i * 16][d];
#pragma unroll
            for (int j = 0; j < 4; ++j) wv[j] = *(const float4*)&wt[a + j * 16][d];
#pragma unroll
            for (int i = 0; i < 4; ++i)
#pragma unroll
                for (int j = 0; j < 4; ++j) {
                    c[i][j] = fmaf(xv[i].x, wv[j].x, c[i][j]);
                    c[i][j] = fmaf(xv[i].y, wv[j].y, c[i][j]);
                    c[i][j] = fmaf(xv[i].z, wv[j].z, c[i][j]);
                    c[i][j] = fmaf(xv[i].w, wv[j].w, c[i][j]);
                }
        }
        __syncthreads();
    }
#pragma unroll
    for (int i = 0; i < 4; ++i)
#pragma unroll
        for (int j = 0; j < 4; ++j)
            xl[bcol + i * 16][a + j * 16] = c[i][j] + br[a + j * 16];
    __syncthreads();

    int w = tid >> 6, lane = tid & 63;
    for (int ti = 0; ti < 16; ++ti) {
        int tl = w * 16 + ti;
        float acc = xl[tl][lane];     // lane == expert
        float v = acc; int idx = lane;
#pragma unroll
        for (int m = 32; m; m >>= 1) {
            float ov = __shfl_xor(v, m); int oi = __shfl_xor(idx, m);
            if (ov > v || (ov == v && oi < idx)) { v = ov; idx = oi; }
        }
        int e0 = idx; float l0 = v;
        float v2 = (lane == e0) ? -3.4e38f : acc; int idx2 = lane;
#pragma unroll
        for (int m = 32; m; m >>= 1) {
            float ov = __shfl_xor(v2, m); int oi = __shfl_xor(idx2, m);
            if (ov > v2 || (ov == v2 && oi < idx2)) { v2 = ov; idx2 = oi; }
        }
        if (lane == 0) {
            int t = tok0 + tl;
            float ex = expf(v2 - l0);         // <= 1
            float g1 = ex / (1.0f + ex);
            topk_e[2 * t] = e0; topk_e[2 * t + 1] = idx2;
            topk_g[2 * t] = 1.0f - g1; topk_g[2 * t + 1] = g1;
            atomicAdd(&lcnt[e0], 1);
            atomicAdd(&lcnt[idx2], 1);
        }
    }
    __syncthreads();
    if (tid < NEXP) atomicAdd(&cnt[tid], lcnt[tid]);
}

// ---------------------------------------------------------------------------
// K2: scatter with in-block scan of cnt (wave 0); block 0 publishes the
// global offs / tileOffs prefixes for the FFN kernel.
__global__ __launch_bounds__(256) void scatter_kernel(const int* __restrict__ topk_e,
                                                      const float* __restrict__ topk_g,
                                                      const int* __restrict__ cnt,
                                                      int* __restrict__ cursor,
                                                      int* __restrict__ perm,
                                                      float* __restrict__ pgate,
                                                      int* __restrict__ offs_g,
                                                      int* __restrict__ tileOffs_g) {
    __shared__ int lcnt[NEXP], lbase[NEXP], sOffs[NEXP];
    int tid = threadIdx.x;
    if (tid < NEXP) lcnt[tid] = 0;
    if (tid < 64) {   // wave 0: exclusive scans
        int c = cnt[tid];
        int t = (c + TM - 1) / TM;
        int ic = c, it = t;
#pragma unroll
        for (int d = 1; d < 64; d <<= 1) {
            int vc = __shfl_up(ic, d), vt = __shfl_up(it, d);
            if (tid >= d) { ic += vc; it += vt; }
        }
        sOffs[tid] = ic - c;
        if (blockIdx.x == 0) {
            offs_g[tid] = ic - c;
            tileOffs_g[tid] = it - t;
            if (tid == 63) { offs_g[64] = ic; tileOffs_g[64] = it; }
        }
    }
    __syncthreads();
    int t = blockIdx.x * 256 + tid;
    int e0 = topk_e[2 * t], e1 = topk_e[2 * t + 1];
    int i0 = atomicAdd(&lcnt[e0], 1);
    int i1 = atomicAdd(&lcnt[e1], 1);
    __syncthreads();
    if (tid < NEXP) lbase[tid] = atomicAdd(&cursor[tid], lcnt[tid]);
    __syncthreads();
    int p0 = sOffs[e0] + lbase[e0] + i0;
    int p1 = sOffs[e1] + lbase[e1] + i1;
    perm[p0] = t; pgate[p0] = topk_g[2 * t];
    perm[p1] = t; pgate[p1] = topk_g[2 * t + 1];
}

// ---------------------------------------------------------------------------
// Expert FFN v3: TM=64. Block = (expert, 64-token tile), 4 waves.
// Each wave holds ALL 4 m-tiles in registers and owns a disjoint N-quarter
// -> every B-fragment load feeds 4 MFMAs; W1+W2 read exactly once per block.
// LDS union: x-tile (cols 0..255) consumed into regs before layer 1, then the
// same buffer holds H (cols 0..511): 66.5 KB -> 2 blocks/CU (8 waves/CU).
// MFMA 16x16x32 bf16 layouts (verified): A[m=lane&15][k=(lane>>4)*8+j];
// C/D col=lane&15, row=(lane>>4)*4+reg.
__global__ __launch_bounds__(256, 2) void expert_ffn(const float* __restrict__ x,
                                                     const uint4* __restrict__ W1f,
                                                     const uint4* __restrict__ W2f,
                                                     const float* __restrict__ b1,
                                                     const float* __restrict__ b2,
                                                     const int* __restrict__ cnt,
                                                     const int* __restrict__ offs,
                                                     const int* __restrict__ tileOffs,
                                                     const int* __restrict__ perm,
                                                     const float* __restrict__ pgate,
                                                     float* __restrict__ out) {
    __shared__ unsigned short smem[TM][DHID + 8];   // 66,560 B: xs then hs
    __shared__ int toks[TM];
    __shared__ float gs[TM];
    __shared__ int tOffs[NEXP + 1];

    int tid = threadIdx.x;
    if (tid <= NEXP) tOffs[tid] = tileOffs[tid];
    __syncthreads();
    int bid = blockIdx.x;
    if (bid >= tOffs[NEXP]) return;
    // largest e with tOffs[e] <= bid (empty experts have zero-width ranges)
    int lo = 0, hi = NEXP;
    while (hi - lo > 1) { int mid = (lo + hi) >> 1; if (tOffs[mid] <= bid) lo = mid; else hi = mid; }
    int e = lo;
    int ne = cnt[e];
    int tile0 = (bid - tOffs[e]) * TM;

    if (tid < TM) {
        int idx = tile0 + tid;
        if (idx < ne) {
            int p = offs[e] + idx;
            toks[tid] = perm[p]; gs[tid] = pgate[p];
        } else {
            toks[tid] = 0; gs[tid] = 0.0f;   // padded slot: gate 0 -> no-op add
        }
    }
    __syncthreads();
    {   // gather x rows -> LDS bf16 (cols 0..255); 4 threads per row
        int row = tid >> 2, c0 = (tid & 3) * 64;
        const float4* src = (const float4*)(x + (size_t)toks[row] * DIN + c0);
        unsigned* dst = (unsigned*)&smem[row][c0];
#pragma unroll
        for (int i = 0; i < 16; ++i) {
            float4 v = src[i];
            dst[2 * i]     = pack2(v.x, v.y);
            dst[2 * i + 1] = pack2(v.z, v.w);
        }
    }
    __syncthreads();

    int w = tid >> 6, lane = tid & 63;
    int quad = lane >> 4, lr = lane & 15;

    // ---- pull entire X tile into regs (all 4 m-tiles, all K) ----
    short8 a1[4][8];
#pragma unroll
    for (int mt = 0; mt < 4; ++mt)
#pragma unroll
        for (int kk = 0; kk < 8; ++kk)
            a1[mt][kk] = *(const short8*)&smem[mt * 16 + lr][kk * 32 + quad * 8];
    __syncthreads();   // xs fully consumed; smem becomes hs

    // ---- layer 1: H = relu(X @ W1[e] + b1[e]); wave w -> n in [w*128,(w+1)*128)
    const uint4* bbase1 = W1f + (size_t)e * 16384 + (size_t)(w * 8) * 512 + lane;
#pragma unroll
    for (int i = 0; i < 8; ++i) {
        const uint4* bp = bbase1 + (size_t)i * 512;
        uint4 braw[8];
#pragma unroll
        for (int kk = 0; kk < 8; ++kk) braw[kk] = bp[kk * 64];
        f32x4 acc[4];
#pragma unroll
        for (int mt = 0; mt < 4; ++mt) acc[mt] = (f32x4){0.0f, 0.0f, 0.0f, 0.0f};
#pragma unroll
        for (int kk = 0; kk < 8; ++kk) {
            short8 b = __builtin_bit_cast(short8, braw[kk]);
#pragma unroll
            for (int mt = 0; mt < 4; ++mt)
                acc[mt] = __builtin_amdgcn_mfma_f32_16x16x32_bf16(a1[mt][kk], b, acc[mt], 0, 0, 0);
        }
        int n = w * 128 + i * 16;
        float bias = b1[e * DHID + n + lr];
#pragma unroll
        for (int mt = 0; mt < 4; ++mt)
#pragma unroll
            for (int r = 0; r < 4; ++r)
                smem[mt * 16 + quad * 4 + r][n + lr] = f2bf(fmaxf(acc[mt][r] + bias, 0.0f));
    }
    __syncthreads();

    // ---- layer 2: Y = H @ W2[e] + b2[e]; wave w -> n in [w*64, w*64+64)
    // K in 4 quarters to bound registers (a2 = 64 VGPRs at a time).
    f32x4 acc2[4][4];   // [n-tile][m-tile]
#pragma unroll
    for (int i = 0; i < 4; ++i)
#pragma unroll
        for (int mt = 0; mt < 4; ++mt)
            acc2[i][mt] = (f32x4){0.0f, 0.0f, 0.0f, 0.0f};
    for (int h = 0; h < 4; ++h) {
        short8 a2[4][4];
#pragma unroll
        for (int mt = 0; mt < 4; ++mt)
#pragma unroll
            for (int kk = 0; kk < 4; ++kk)
                a2[mt][kk] = *(const short8*)&smem[mt * 16 + lr][h * 128 + kk * 32 + quad * 8];
#pragma unroll
        for (int i = 0; i < 4; ++i) {
            int ng = w * 4 + i;            // global 16-wide n-tile
            const uint4* bp = W2f + (size_t)e * 16384 + (size_t)ng * 1024 + (size_t)h * 256 + lane;
            uint4 braw[4];
#pragma unroll
            for (int kk = 0; kk < 4; ++kk) braw[kk] = bp[kk * 64];
#pragma unroll
            for (int kk = 0; kk < 4; ++kk) {
                short8 b = __builtin_bit_cast(short8, braw[kk]);
#pragma unroll
                for (int mt = 0; mt < 4; ++mt)
                    acc2[i][mt] = __builtin_amdgcn_mfma_f32_16x16x32_bf16(a2[mt][kk], b, acc2[i][mt], 0, 0, 0);
            }
        }
    }
    // ---- epilogue: out[tok] += gate * (y + b2) ----
#pragma unroll
    for (int i = 0; i < 4; ++i) {
        int n = w * 64 + i * 16;
        float bias = b2[e * DOUT + n + lr];
#pragma unroll
        for (int mt = 0; mt < 4; ++mt)
#pragma unroll
            for (int r = 0; r < 4; ++r) {
                int m = mt * 16 + quad * 4 + r;
                float y = acc2[i][mt][r] + bias;
                atomicAdd(&out[(size_t)toks[m] * DOUT + n + lr], gs[m] * y);
            }
    }
}

// ---------------------------------------------------------------------------
extern "C" void kernel_launch(void* const* d_in, const int* in_sizes, int n_in,
                              void* d_out, int out_size, void* d_ws, size_t ws_size,
                              hipStream_t stream) {
    (void)in_sizes; (void)n_in; (void)ws_size;   // needs ws_size >= ~34.6 MB
    const float* x  = (const float*)d_in[0];
    const float* Wr = (const float*)d_in[1];
    const float* br = (const float*)d_in[2];
    const float* W1 = (const float*)d_in[3];
    const float* b1 = (const float*)d_in[4];
    const float* W2 = (const float*)d_in[5];
    const float* b2 = (const float*)d_in[6];
    float* out = (float*)d_out;
    char* ws = (char*)d_ws;

    uint4* W1f     = (uint4*)(ws + OFF_W1F);
    uint4* W2f     = (uint4*)(ws + OFF_W2F);
    int*   cnt     = (int*)(ws + OFF_CNT);
    int*   cursor  = (int*)(ws + OFF_CUR);
    int*   offs    = (int*)(ws + OFF_OFFS);
    int*   tileOff = (int*)(ws + OFF_TILE);
    int*   topk_e  = (int*)(ws + OFF_TOPKE);
    float* topk_g  = (float*)(ws + OFF_TOPKG);
    int*   perm    = (int*)(ws + OFF_PERM);
    float* pgate   = (float*)(ws + OFF_PGATE);

    hipMemsetAsync(out, 0, (size_t)out_size * sizeof(float), stream);
    hipMemsetAsync(ws + OFF_CNT, 0, 512, stream);   // cnt + cursor

    router_prep<<<ROUTER_BLOCKS + PREP_BLOCKS, 256, 0, stream>>>(
        x, Wr, br, W1, W2, W1f, W2f, topk_e, topk_g, cnt);
    scatter_kernel<<<T_TOK / 256, 256, 0, stream>>>(topk_e, topk_g, cnt, cursor,
                                                    perm, pgate, offs, tileOff);
    expert_ffn<<<MAXTILES, 256, 0, stream>>>(x, W1f, W2f, b1, b2, cnt, offs, tileOff,
                                             perm, pgate, out);
}

// Round 4
// 356.484 us; speedup vs baseline: 1.2194x; 1.2194x over previous
//
#include <hip/hip_runtime.h>
#include <stdint.h>

// Problem constants (fixed by reference)
#define T_TOK 32768   // B*S = 8*4096
#define DIN   256
#define DHID  512
#define DOUT  256
#define NEXP  64
#define TM    32      // tokens per expert-FFN tile
#define FFN_BLOCKS 2048                    // 8 XCD groups x 256 slots (persistent-ish)
#define ROUTER_BLOCKS (T_TOK / 64)         // 512
#define PREP_BLOCKS   8192

typedef __attribute__((ext_vector_type(8))) short short8;   // 8 bf16 (4 VGPRs)
typedef __attribute__((ext_vector_type(4))) float f32x4;

// ---- workspace layout (bytes) ----  total ~34.6 MB
#define OFF_W1F   0u                       // 16 MiB bf16 fragment-ordered W1
#define OFF_W2F   16777216u                // 16 MiB bf16 fragment-ordered W2
#define OFF_BASE  33554432u
#define OFF_CNT   (OFF_BASE + 0u)          // 64 int
#define OFF_CUR   (OFF_BASE + 256u)        // 64 int
#define OFF_OFFS  (OFF_BASE + 512u)        // 65 int (token-slot prefix)
#define OFF_GOFF  (OFF_BASE + 1024u)       // 8 groups x 9 int (per-XCD tile prefix)
#define OFF_TOPKE (OFF_BASE + 2048u)       // 2T int
#define OFF_TOPKG (OFF_TOPKE + 262144u)    // 2T float
#define OFF_PERM  (OFF_TOPKG + 262144u)    // 2T int
#define OFF_PGATE (OFF_PERM + 262144u)     // 2T float

__device__ __forceinline__ unsigned short f2bf(float f) {
    union { float f; unsigned u; } a; a.f = f;
    unsigned u = a.u;
    u += 0x7fffu + ((u >> 16) & 1u);   // RNE
    return (unsigned short)(u >> 16);
}
__device__ __forceinline__ unsigned pack2(float a, float b) {
    return (unsigned)f2bf(a) | ((unsigned)f2bf(b) << 16);
}

// async global->LDS DMA, 16B per lane; LDS dest = wave-uniform base + lane*16
__device__ __forceinline__ void async_copy16(const uint4* g, uint4* l) {
    __builtin_amdgcn_global_load_lds(
        (const __attribute__((address_space(1))) unsigned int*)g,
        (__attribute__((address_space(3))) unsigned int*)l, 16, 0, 0);
}

// ---------------------------------------------------------------------------
// Fused K1: blocks [0,512) = router; [512, 8704) = weight prep (fp32 -> bf16
// MFMA B-fragment order). B-fragment order: per 16(N)x32(K) tile, lane l holds
// B[k=kt*32+(l>>4)*8+j][n=nt*16+(l&15)], 64 lanes * 16B contiguous.
__global__ __launch_bounds__(256) void router_prep(const float* __restrict__ x,
                                                   const float* __restrict__ Wr,
                                                   const float* __restrict__ br,
                                                   const float* __restrict__ W1,
                                                   const float* __restrict__ W2,
                                                   uint4* __restrict__ W1f,
                                                   uint4* __restrict__ W2f,
                                                   int* __restrict__ topk_e,
                                                   float* __restrict__ topk_g,
                                                   int* __restrict__ cnt) {
    __shared__ float xl[64][68];   // x chunk [tok][d], later logits [tok][e]
    __shared__ float wt[64][68];   // Wr transposed chunk [e][d]
    __shared__ int lcnt[NEXP];
    int tid = threadIdx.x;

    if (blockIdx.x >= ROUTER_BLOCKS) {
        // ---------------- weight prep ----------------
        int g = (blockIdx.x - ROUTER_BLOCKS) * 256 + tid;   // 0 .. 2*2^20-1
        int isW2 = g >> 20;
        int gg = g & ((1 << 20) - 1);
        int l = gg & 63;
        int t = gg >> 6;            // tile id over all experts
        int e = t >> 8;
        int rem = t & 255;
        int quad = l >> 4, lr = l & 15;
        float v[8];
        if (!isW2) {
            int nt = rem >> 3, kt = rem & 7;          // 32 n-tiles, 8 k-tiles
            int kb = kt * 32 + quad * 8;
            int n = nt * 16 + lr;
            const float* s = W1 + (size_t)e * DIN * DHID + n;
#pragma unroll
            for (int j = 0; j < 8; ++j) v[j] = s[(size_t)(kb + j) * DHID];
        } else {
            int nt = rem >> 4, kt = rem & 15;         // 16 n-tiles, 16 k-tiles
            int kb = kt * 32 + quad * 8;
            int n = nt * 16 + lr;
            const float* s = W2 + (size_t)e * DHID * DOUT + n;
#pragma unroll
            for (int j = 0; j < 8; ++j) v[j] = s[(size_t)(kb + j) * DOUT];
        }
        uint4 o;
        o.x = pack2(v[0], v[1]); o.y = pack2(v[2], v[3]);
        o.z = pack2(v[4], v[5]); o.w = pack2(v[6], v[7]);
        (isW2 ? W2f : W1f)[gg] = o;
        return;
    }

    // ---------------- router (fp32 logits; bf16 would swap near-tie picks) --
    if (tid < NEXP) lcnt[tid] = 0;
    int a = tid >> 4;        // expert group base
    int bcol = tid & 15;     // token group base
    int tok0 = blockIdx.x * 64;
    float c[4][4];
#pragma unroll
    for (int i = 0; i < 4; ++i)
#pragma unroll
        for (int j = 0; j < 4; ++j) c[i][j] = 0.0f;

    for (int chunk = 0; chunk < 4; ++chunk) {
        int d0 = chunk * 64;
        {   // stage x[tok0..tok0+63][d0..d0+63]
            int tok = tid >> 2, off = (tid & 3) * 16;
            const float4* s = (const float4*)(x + (size_t)(tok0 + tok) * DIN + d0 + off);
            float4* d = (float4*)&xl[tok][off];
#pragma unroll
            for (int i = 0; i < 4; ++i) d[i] = s[i];
        }
        {   // stage Wr chunk transposed: wt[e][dd] = Wr[d0+dd][e]
            int dd = tid >> 2, ecol = (tid & 3) * 16;
            const float* s = Wr + (size_t)(d0 + dd) * NEXP + ecol;
#pragma unroll
            for (int j = 0; j < 16; ++j) wt[ecol + j][dd] = s[j];
        }
        __syncthreads();
#pragma unroll 4
        for (int d = 0; d < 64; d += 4) {
            float4 xv[4], wv[4];
#pragma unroll
            for (int i = 0; i < 4; ++i) xv[i] = *(const float4*)&xl[bcol + i * 16][d];
#pragma unroll
            for (int j = 0; j < 4; ++j) wv[j] = *(const float4*)&wt[a + j * 16][d];
#pragma unroll
            for (int i = 0; i < 4; ++i)
#pragma unroll
                for (int j = 0; j < 4; ++j) {
                    c[i][j] = fmaf(xv[i].x, wv[j].x, c[i][j]);
                    c[i][j] = fmaf(xv[i].y, wv[j].y, c[i][j]);
                    c[i][j] = fmaf(xv[i].z, wv[j].z, c[i][j]);
                    c[i][j] = fmaf(xv[i].w, wv[j].w, c[i][j]);
                }
        }
        __syncthreads();
    }
#pragma unroll
    for (int i = 0; i < 4; ++i)
#pragma unroll
        for (int j = 0; j < 4; ++j)
            xl[bcol + i * 16][a + j * 16] = c[i][j] + br[a + j * 16];
    __syncthreads();

    int w = tid >> 6, lane = tid & 63;
    for (int ti = 0; ti < 16; ++ti) {
        int tl = w * 16 + ti;
        float acc = xl[tl][lane];     // lane == expert
        float v = acc; int idx = lane;
#pragma unroll
        for (int m = 32; m; m >>= 1) {
            float ov = __shfl_xor(v, m); int oi = __shfl_xor(idx, m);
            if (ov > v || (ov == v && oi < idx)) { v = ov; idx = oi; }
        }
        int e0 = idx; float l0 = v;
        float v2 = (lane == e0) ? -3.4e38f : acc; int idx2 = lane;
#pragma unroll
        for (int m = 32; m; m >>= 1) {
            float ov = __shfl_xor(v2, m); int oi = __shfl_xor(idx2, m);
            if (ov > v2 || (ov == v2 && oi < idx2)) { v2 = ov; idx2 = oi; }
        }
        if (lane == 0) {
            int t = tok0 + tl;
            float ex = expf(v2 - l0);         // <= 1
            float g1 = ex / (1.0f + ex);
            topk_e[2 * t] = e0; topk_e[2 * t + 1] = idx2;
            topk_g[2 * t] = 1.0f - g1; topk_g[2 * t + 1] = g1;
            atomicAdd(&lcnt[e0], 1);
            atomicAdd(&lcnt[idx2], 1);
        }
    }
    __syncthreads();
    if (tid < NEXP) atomicAdd(&cnt[tid], lcnt[tid]);
}

// ---------------------------------------------------------------------------
// K2: scatter; wave 0 also scans cnt. Block 0 publishes offs (token-slot
// prefix) and gOffs (per-XCD-group tile prefix over that group's 8 experts).
__global__ __launch_bounds__(256) void scatter_kernel(const int* __restrict__ topk_e,
                                                      const float* __restrict__ topk_g,
                                                      const int* __restrict__ cnt,
                                                      int* __restrict__ cursor,
                                                      int* __restrict__ perm,
                                                      float* __restrict__ pgate,
                                                      int* __restrict__ offs_g,
                                                      int* __restrict__ gOffs_g) {
    __shared__ int lcnt[NEXP], lbase[NEXP], sOffs[NEXP];
    int tid = threadIdx.x;
    if (tid < NEXP) lcnt[tid] = 0;
    if (tid < 64) {   // wave 0
        int c = cnt[tid];
        int ic = c;
#pragma unroll
        for (int d = 1; d < 64; d <<= 1) {
            int vc = __shfl_up(ic, d);
            if (tid >= d) ic += vc;
        }
        sOffs[tid] = ic - c;
        if (blockIdx.x == 0) {
            offs_g[tid] = ic - c;
            if (tid == 63) offs_g[64] = ic;
            // per-XCD-group tile prefix: experts e = q + 8j for group q
            int tiles = (c + TM - 1) / TM;
            int q = tid & 7, j = tid >> 3;
            int pre = 0, tot = 0;
            for (int jj = 0; jj < 8; ++jj) {
                int v = __shfl(tiles, q + 8 * jj);
                tot += v;
                if (jj < j) pre += v;
            }
            gOffs_g[q * 9 + j] = pre;
            if (j == 7) gOffs_g[q * 9 + 8] = tot;
        }
    }
    __syncthreads();
    int t = blockIdx.x * 256 + tid;
    int e0 = topk_e[2 * t], e1 = topk_e[2 * t + 1];
    int i0 = atomicAdd(&lcnt[e0], 1);
    int i1 = atomicAdd(&lcnt[e1], 1);
    __syncthreads();
    if (tid < NEXP) lbase[tid] = atomicAdd(&cursor[tid], lcnt[tid]);
    __syncthreads();
    int p0 = sOffs[e0] + lbase[e0] + i0;
    int p1 = sOffs[e1] + lbase[e1] + i1;
    perm[p0] = t; pgate[p0] = topk_g[2 * t];
    perm[p1] = t; pgate[p1] = topk_g[2 * t + 1];
}

// ---------------------------------------------------------------------------
// Expert FFN v4: persistent grid (2048 blocks). Block bid serves XCD group
// q=bid&7 (experts e%8==q -> weights stay L2-resident on one XCD), looping
// tiles s = slot, slot+256, ... 4 waves, wave w owns N-quarter, computes both
// 16-row m-tiles. B staged via global_load_lds into per-wave 2x4KB ring with
// fine-grained vmcnt(4) waits (AITER-style pipeline, no per-chunk barriers).
// x A-frags direct from global; H via LDS (pad->stride 520 u16, conflict-ok);
// biases via LDS; layer-2 atomics deferred past the pipeline.
// MFMA 16x16x32 bf16 layouts: A[m=lane&15][k=(lane>>4)*8+j];
// C/D col=lane&15, row=(lane>>4)*4+reg.
__global__ __launch_bounds__(256, 2) void expert_ffn(const float* __restrict__ x,
                                                     const uint4* __restrict__ W1f,
                                                     const uint4* __restrict__ W2f,
                                                     const float* __restrict__ b1,
                                                     const float* __restrict__ b2,
                                                     const int* __restrict__ cnt,
                                                     const int* __restrict__ offs,
                                                     const int* __restrict__ gOffs,
                                                     const int* __restrict__ perm,
                                                     const float* __restrict__ pgate,
                                                     float* __restrict__ out) {
    __shared__ unsigned short Hs[TM][DHID + 8];   // 33,280 B
    __shared__ uint4 Bst[4][2][256];              // 4 waves x dbuf x 4KB = 32 KB
    __shared__ float bias1s[DHID];                // 2 KB
    __shared__ float bias2s[DOUT];                // 1 KB
    __shared__ int toks[TM];
    __shared__ float gs[TM];
    __shared__ int sOff[9];

    int tid = threadIdx.x;
    int q = blockIdx.x & 7, slot = blockIdx.x >> 3;
    if (tid < 9) sOff[tid] = gOffs[q * 9 + tid];
    __syncthreads();
    int L = sOff[8];
    int w = tid >> 6, lane = tid & 63, quad = lane >> 4, lr = lane & 15;

    for (int s = slot; s < L; s += 256) {
        // expert within group (8 experts, zero-width ranges for empty)
        int j = 0;
#pragma unroll
        for (int jj = 1; jj < 8; ++jj) j += (sOff[jj] <= s) ? 1 : 0;
        int e = q + 8 * j;
        int ne = cnt[e];
        int tile0 = (s - sOff[j]) * TM;

        __syncthreads();   // prev iteration fully done with toks/gs/bias/Hs
        if (tid < TM) {
            int idx = tile0 + tid;
            if (idx < ne) { int p = offs[e] + idx; toks[tid] = perm[p]; gs[tid] = pgate[p]; }
            else          { toks[tid] = 0; gs[tid] = 0.0f; }   // gate 0 -> no-op
        }
        if (tid < 128)
            *(float4*)&bias1s[tid * 4] = *(const float4*)(b1 + (size_t)e * DHID + tid * 4);
        else if (tid < 192)
            *(float4*)&bias2s[(tid - 128) * 4] = *(const float4*)(b2 + (size_t)e * DOUT + (tid - 128) * 4);
        __syncthreads();

        auto stage1 = [&](int c) {   // chunk c: n-tile i=c>>1 (ng=w+4*i), half c&1
            const uint4* g = W1f + (size_t)e * 16384 + (size_t)(w + 4 * (c >> 1)) * 512
                           + (size_t)(c & 1) * 256 + lane;
#pragma unroll
            for (int f = 0; f < 4; ++f) async_copy16(g + f * 64, &Bst[w][c & 1][f * 64]);
        };
        auto stage2 = [&](int c) {   // chunk c: n-tile i=c>>2 (ng=w+4*i), k-quarter c&3
            const uint4* g = W2f + (size_t)e * 16384 + (size_t)(w + 4 * (c >> 2)) * 1024
                           + (size_t)(c & 3) * 256 + lane;
#pragma unroll
            for (int f = 0; f < 4; ++f) async_copy16(g + f * 64, &Bst[w][c & 1][f * 64]);
        };

        stage1(0); stage1(1);   // prefetch while x-gather runs

        // ---- x A-frags direct from global (fp32 -> bf16) ----
        short8 a1[2][8];
#pragma unroll
        for (int mt = 0; mt < 2; ++mt) {
            const float* xr = x + (size_t)toks[mt * 16 + lr] * DIN + quad * 8;
#pragma unroll
            for (int kk = 0; kk < 8; ++kk) {
                float4 u = *(const float4*)(xr + kk * 32);
                float4 v = *(const float4*)(xr + kk * 32 + 4);
                short8 t;
                t[0] = (short)f2bf(u.x); t[1] = (short)f2bf(u.y);
                t[2] = (short)f2bf(u.z); t[3] = (short)f2bf(u.w);
                t[4] = (short)f2bf(v.x); t[5] = (short)f2bf(v.y);
                t[6] = (short)f2bf(v.z); t[7] = (short)f2bf(v.w);
                a1[mt][kk] = t;
            }
        }

        // ---- layer 1 pipeline: 16 chunks (8 n-tiles x 2 halves) ----
        f32x4 acc0 = {0.f,0.f,0.f,0.f}, acc1 = {0.f,0.f,0.f,0.f};
#pragma unroll
        for (int c = 0; c < 16; ++c) {
            if ((c & 1) == 0) { acc0 = (f32x4){0.f,0.f,0.f,0.f}; acc1 = (f32x4){0.f,0.f,0.f,0.f}; }
            if (c < 14) __builtin_amdgcn_s_waitcnt(0x0F74);   // vmcnt(4): c done, c+1 in flight
            else        __builtin_amdgcn_s_waitcnt(0x0F70);   // vmcnt(0)
            const uint4* bb = &Bst[w][c & 1][0];
#pragma unroll
            for (int f = 0; f < 4; ++f) {
                short8 b = *(const short8*)&bb[f * 64 + lane];
                int kk = (c & 1) * 4 + f;
                acc0 = __builtin_amdgcn_mfma_f32_16x16x32_bf16(a1[0][kk], b, acc0, 0, 0, 0);
                acc1 = __builtin_amdgcn_mfma_f32_16x16x32_bf16(a1[1][kk], b, acc1, 0, 0, 0);
            }
            if (c + 2 < 16) stage1(c + 2);   // after ds_reads consumed (MFMA waits)
            if (c & 1) {
                int n = (w + 4 * (c >> 1)) * 16;
                float bias = bias1s[n + lr];
#pragma unroll
                for (int r = 0; r < 4; ++r) {
                    Hs[quad * 4 + r][n + lr]      = f2bf(fmaxf(acc0[r] + bias, 0.0f));
                    Hs[16 + quad * 4 + r][n + lr] = f2bf(fmaxf(acc1[r] + bias, 0.0f));
                }
            }
        }

        stage2(0); stage2(1);
        __syncthreads();   // H complete (drains DMA too; once per tile)

        // ---- layer 2 pipeline: 16 chunks (4 n-tiles x 4 k-quarters) ----
        f32x4 acc2[4][2];
#pragma unroll
        for (int i = 0; i < 4; ++i)
#pragma unroll
            for (int mt = 0; mt < 2; ++mt) acc2[i][mt] = (f32x4){0.f,0.f,0.f,0.f};
#pragma unroll
        for (int c = 0; c < 16; ++c) {
            if (c < 14) __builtin_amdgcn_s_waitcnt(0x0F74);
            else        __builtin_amdgcn_s_waitcnt(0x0F70);
            const uint4* bb = &Bst[w][c & 1][0];
            int i2 = c >> 2;
#pragma unroll
            for (int f = 0; f < 4; ++f) {
                short8 b = *(const short8*)&bb[f * 64 + lane];
                int kk = (c & 3) * 4 + f;
                short8 a0 = *(const short8*)&Hs[lr][kk * 32 + quad * 8];
                short8 a1v = *(const short8*)&Hs[16 + lr][kk * 32 + quad * 8];
                acc2[i2][0] = __builtin_amdgcn_mfma_f32_16x16x32_bf16(a0, b, acc2[i2][0], 0, 0, 0);
                acc2[i2][1] = __builtin_amdgcn_mfma_f32_16x16x32_bf16(a1v, b, acc2[i2][1], 0, 0, 0);
            }
            if (c + 2 < 16) stage2(c + 2);
        }

        // ---- deferred epilogue: out[tok] += gate * (y + b2) ----
#pragma unroll
        for (int i = 0; i < 4; ++i) {
            int n = (w + 4 * i) * 16;
            float bias = bias2s[n + lr];
#pragma unroll
            for (int mt = 0; mt < 2; ++mt)
#pragma unroll
                for (int r = 0; r < 4; ++r) {
                    int m = mt * 16 + quad * 4 + r;
                    atomicAdd(&out[(size_t)toks[m] * DOUT + n + lr],
                              gs[m] * (acc2[i][mt][r] + bias));
                }
        }
    }
}

// ---------------------------------------------------------------------------
extern "C" void kernel_launch(void* const* d_in, const int* in_sizes, int n_in,
                              void* d_out, int out_size, void* d_ws, size_t ws_size,
                              hipStream_t stream) {
    (void)in_sizes; (void)n_in; (void)ws_size;   // needs ws_size >= ~34.6 MB
    const float* x  = (const float*)d_in[0];
    const float* Wr = (const float*)d_in[1];
    const float* br = (const float*)d_in[2];
    const float* W1 = (const float*)d_in[3];
    const float* b1 = (const float*)d_in[4];
    const float* W2 = (const float*)d_in[5];
    const float* b2 = (const float*)d_in[6];
    float* out = (float*)d_out;
    char* ws = (char*)d_ws;

    uint4* W1f    = (uint4*)(ws + OFF_W1F);
    uint4* W2f    = (uint4*)(ws + OFF_W2F);
    int*   cnt    = (int*)(ws + OFF_CNT);
    int*   cursor = (int*)(ws + OFF_CUR);
    int*   offs   = (int*)(ws + OFF_OFFS);
    int*   gOffs  = (int*)(ws + OFF_GOFF);
    int*   topk_e = (int*)(ws + OFF_TOPKE);
    float* topk_g = (float*)(ws + OFF_TOPKG);
    int*   perm   = (int*)(ws + OFF_PERM);
    float* pgate  = (float*)(ws + OFF_PGATE);

    hipMemsetAsync(out, 0, (size_t)out_size * sizeof(float), stream);
    hipMemsetAsync(ws + OFF_CNT, 0, 512, stream);   // cnt + cursor

    router_prep<<<ROUTER_BLOCKS + PREP_BLOCKS, 256, 0, stream>>>(
        x, Wr, br, W1, W2, W1f, W2f, topk_e, topk_g, cnt);
    scatter_kernel<<<T_TOK / 256, 256, 0, stream>>>(topk_e, topk_g, cnt, cursor,
                                                    perm, pgate, offs, gOffs);
    expert_ffn<<<FFN_BLOCKS, 256, 0, stream>>>(x, W1f, W2f, b1, b2, cnt, offs, gOffs,
                                               perm, pgate, out);
}

// Round 5
// 343.472 us; speedup vs baseline: 1.2656x; 1.0379x over previous
//
#include <hip/hip_runtime.h>
#include <stdint.h>

// Problem constants (fixed by reference)
#define T_TOK 32768   // B*S = 8*4096
#define DIN   256
#define DHID  512
#define DOUT  256
#define NEXP  64
#define TM    32      // tokens per expert-FFN tile
#define FFN_BLOCKS 2048                    // 8 XCD groups x 256 slots
#define ROUTER_BLOCKS (T_TOK / 64)         // 512
#define PREP_BLOCKS   8192
#define OUTZ_BLOCKS   512                  // zero d_out (8.39M floats = 512*256*16 f4)

typedef __attribute__((ext_vector_type(8))) short short8;   // 8 bf16 (4 VGPRs)
typedef __attribute__((ext_vector_type(4))) float f32x4;

// ---- workspace layout (bytes) ----  total ~34.6 MB
#define OFF_W1F   0u                       // 16 MiB bf16 fragment-ordered W1
#define OFF_W2F   16777216u                // 16 MiB bf16 fragment-ordered W2
#define OFF_BASE  33554432u
#define OFF_CNT   (OFF_BASE + 0u)          // 64 int
#define OFF_CUR   (OFF_BASE + 256u)        // 64 int
#define OFF_OFFS  (OFF_BASE + 512u)        // 65 int (token-slot prefix)
#define OFF_GOFF  (OFF_BASE + 1024u)       // 8 groups x 9 int (per-XCD tile prefix)
#define OFF_TOPKE (OFF_BASE + 2048u)       // 2T int
#define OFF_TOPKG (OFF_TOPKE + 262144u)    // 2T float
#define OFF_PERM  (OFF_TOPKG + 262144u)    // 2T int
#define OFF_PGATE (OFF_PERM + 262144u)     // 2T float

__device__ __forceinline__ unsigned short f2bf(float f) {
    union { float f; unsigned u; } a; a.f = f;
    unsigned u = a.u;
    u += 0x7fffu + ((u >> 16) & 1u);   // RNE
    return (unsigned short)(u >> 16);
}
__device__ __forceinline__ unsigned pack2(float a, float b) {
    return (unsigned)f2bf(a) | ((unsigned)f2bf(b) << 16);
}

// async global->LDS DMA, 16B per lane; LDS dest = wave-uniform base + lane*16
__device__ __forceinline__ void async_copy16(const uint4* g, uint4* l) {
    __builtin_amdgcn_global_load_lds(
        (const __attribute__((address_space(1))) unsigned int*)g,
        (__attribute__((address_space(3))) unsigned int*)l, 16, 0, 0);
}

// ---------------------------------------------------------------------------
// Fused K1: blocks [0,512) = router; [512, 8704) = weight prep (fp32 -> bf16
// MFMA B-fragment order); [8704, 9216) = zero d_out (replaces a memset node).
// B-fragment order: per 16(N)x32(K) tile, lane l holds
// B[k=kt*32+(l>>4)*8+j][n=nt*16+(l&15)], 64 lanes * 16B contiguous.
__global__ __launch_bounds__(256) void router_prep(const float* __restrict__ x,
                                                   const float* __restrict__ Wr,
                                                   const float* __restrict__ br,
                                                   const float* __restrict__ W1,
                                                   const float* __restrict__ W2,
                                                   uint4* __restrict__ W1f,
                                                   uint4* __restrict__ W2f,
                                                   int* __restrict__ topk_e,
                                                   float* __restrict__ topk_g,
                                                   int* __restrict__ cnt,
                                                   float4* __restrict__ outz) {
    __shared__ float xl[64][68];   // x chunk [tok][d], later logits [tok][e]
    __shared__ float wt[64][68];   // Wr transposed chunk [e][d]
    __shared__ int lcnt[NEXP];
    int tid = threadIdx.x;

    if (blockIdx.x >= ROUTER_BLOCKS + PREP_BLOCKS) {
        // ---------------- zero d_out ----------------
        int base = (blockIdx.x - (ROUTER_BLOCKS + PREP_BLOCKS)) * 256 + tid;
        float4 z = {0.0f, 0.0f, 0.0f, 0.0f};
#pragma unroll
        for (int i = 0; i < 16; ++i) outz[base + i * (OUTZ_BLOCKS * 256)] = z;
        return;
    }
    if (blockIdx.x >= ROUTER_BLOCKS) {
        // ---------------- weight prep ----------------
        int g = (blockIdx.x - ROUTER_BLOCKS) * 256 + tid;   // 0 .. 2*2^20-1
        int isW2 = g >> 20;
        int gg = g & ((1 << 20) - 1);
        int l = gg & 63;
        int t = gg >> 6;            // tile id over all experts
        int e = t >> 8;
        int rem = t & 255;
        int quad = l >> 4, lr = l & 15;
        float v[8];
        if (!isW2) {
            int nt = rem >> 3, kt = rem & 7;          // 32 n-tiles, 8 k-tiles
            int kb = kt * 32 + quad * 8;
            int n = nt * 16 + lr;
            const float* s = W1 + (size_t)e * DIN * DHID + n;
#pragma unroll
            for (int j = 0; j < 8; ++j) v[j] = s[(size_t)(kb + j) * DHID];
        } else {
            int nt = rem >> 4, kt = rem & 15;         // 16 n-tiles, 16 k-tiles
            int kb = kt * 32 + quad * 8;
            int n = nt * 16 + lr;
            const float* s = W2 + (size_t)e * DHID * DOUT + n;
#pragma unroll
            for (int j = 0; j < 8; ++j) v[j] = s[(size_t)(kb + j) * DOUT];
        }
        uint4 o;
        o.x = pack2(v[0], v[1]); o.y = pack2(v[2], v[3]);
        o.z = pack2(v[4], v[5]); o.w = pack2(v[6], v[7]);
        (isW2 ? W2f : W1f)[gg] = o;
        return;
    }

    // ---------------- router (fp32 logits; bf16 would swap near-tie picks) --
    if (tid < NEXP) lcnt[tid] = 0;
    int a = tid >> 4;        // expert group base
    int bcol = tid & 15;     // token group base
    int tok0 = blockIdx.x * 64;
    float c[4][4];
#pragma unroll
    for (int i = 0; i < 4; ++i)
#pragma unroll
        for (int j = 0; j < 4; ++j) c[i][j] = 0.0f;

    for (int chunk = 0; chunk < 4; ++chunk) {
        int d0 = chunk * 64;
        {   // stage x[tok0..tok0+63][d0..d0+63]
            int tok = tid >> 2, off = (tid & 3) * 16;
            const float4* s = (const float4*)(x + (size_t)(tok0 + tok) * DIN + d0 + off);
            float4* d = (float4*)&xl[tok][off];
#pragma unroll
            for (int i = 0; i < 4; ++i) d[i] = s[i];
        }
        {   // stage Wr chunk transposed: wt[e][dd] = Wr[d0+dd][e]
            int dd = tid >> 2, ecol = (tid & 3) * 16;
            const float* s = Wr + (size_t)(d0 + dd) * NEXP + ecol;
#pragma unroll
            for (int j = 0; j < 16; ++j) wt[ecol + j][dd] = s[j];
        }
        __syncthreads();
#pragma unroll 4
        for (int d = 0; d < 64; d += 4) {
            float4 xv[4], wv[4];
#pragma unroll
            for (int i = 0; i < 4; ++i) xv[i] = *(const float4*)&xl[bcol + i * 16][d];
#pragma unroll
            for (int j = 0; j < 4; ++j) wv[j] = *(const float4*)&wt[a + j * 16][d];
#pragma unroll
            for (int i = 0; i < 4; ++i)
#pragma unroll
                for (int j = 0; j < 4; ++j) {
                    c[i][j] = fmaf(xv[i].x, wv[j].x, c[i][j]);
                    c[i][j] = fmaf(xv[i].y, wv[j].y, c[i][j]);
                    c[i][j] = fmaf(xv[i].z, wv[j].z, c[i][j]);
                    c[i][j] = fmaf(xv[i].w, wv[j].w, c[i][j]);
                }
        }
        __syncthreads();
    }
#pragma unroll
    for (int i = 0; i < 4; ++i)
#pragma unroll
        for (int j = 0; j < 4; ++j)
            xl[bcol + i * 16][a + j * 16] = c[i][j] + br[a + j * 16];
    __syncthreads();

    int w = tid >> 6, lane = tid & 63;
    for (int ti = 0; ti < 16; ++ti) {
        int tl = w * 16 + ti;
        float acc = xl[tl][lane];     // lane == expert
        float v = acc; int idx = lane;
#pragma unroll
        for (int m = 32; m; m >>= 1) {
            float ov = __shfl_xor(v, m); int oi = __shfl_xor(idx, m);
            if (ov > v || (ov == v && oi < idx)) { v = ov; idx = oi; }
        }
        int e0 = idx; float l0 = v;
        float v2 = (lane == e0) ? -3.4e38f : acc; int idx2 = lane;
#pragma unroll
        for (int m = 32; m; m >>= 1) {
            float ov = __shfl_xor(v2, m); int oi = __shfl_xor(idx2, m);
            if (ov > v2 || (ov == v2 && oi < idx2)) { v2 = ov; idx2 = oi; }
        }
        if (lane == 0) {
            int t = tok0 + tl;
            float ex = expf(v2 - l0);         // <= 1
            float g1 = ex / (1.0f + ex);
            topk_e[2 * t] = e0; topk_e[2 * t + 1] = idx2;
            topk_g[2 * t] = 1.0f - g1; topk_g[2 * t + 1] = g1;
            atomicAdd(&lcnt[e0], 1);
            atomicAdd(&lcnt[idx2], 1);
        }
    }
    __syncthreads();
    if (tid < NEXP) atomicAdd(&cnt[tid], lcnt[tid]);
}

// ---------------------------------------------------------------------------
// K2: scatter; wave 0 also scans cnt. Block 0 publishes offs (token-slot
// prefix) and gOffs (per-XCD-group tile prefix over that group's 8 experts).
__global__ __launch_bounds__(256) void scatter_kernel(const int* __restrict__ topk_e,
                                                      const float* __restrict__ topk_g,
                                                      const int* __restrict__ cnt,
                                                      int* __restrict__ cursor,
                                                      int* __restrict__ perm,
                                                      float* __restrict__ pgate,
                                                      int* __restrict__ offs_g,
                                                      int* __restrict__ gOffs_g) {
    __shared__ int lcnt[NEXP], lbase[NEXP], sOffs[NEXP];
    int tid = threadIdx.x;
    if (tid < NEXP) lcnt[tid] = 0;
    if (tid < 64) {   // wave 0
        int c = cnt[tid];
        int ic = c;
#pragma unroll
        for (int d = 1; d < 64; d <<= 1) {
            int vc = __shfl_up(ic, d);
            if (tid >= d) ic += vc;
        }
        sOffs[tid] = ic - c;
        if (blockIdx.x == 0) {
            offs_g[tid] = ic - c;
            if (tid == 63) offs_g[64] = ic;
            // per-XCD-group tile prefix: experts e = q + 8j for group q
            int tiles = (c + TM - 1) / TM;
            int q = tid & 7, j = tid >> 3;
            int pre = 0, tot = 0;
            for (int jj = 0; jj < 8; ++jj) {
                int v = __shfl(tiles, q + 8 * jj);
                tot += v;
                if (jj < j) pre += v;
            }
            gOffs_g[q * 9 + j] = pre;
            if (j == 7) gOffs_g[q * 9 + 8] = tot;
        }
    }
    __syncthreads();
    int t = blockIdx.x * 256 + tid;
    int e0 = topk_e[2 * t], e1 = topk_e[2 * t + 1];
    int i0 = atomicAdd(&lcnt[e0], 1);
    int i1 = atomicAdd(&lcnt[e1], 1);
    __syncthreads();
    if (tid < NEXP) lbase[tid] = atomicAdd(&cursor[tid], lcnt[tid]);
    __syncthreads();
    int p0 = sOffs[e0] + lbase[e0] + i0;
    int p1 = sOffs[e1] + lbase[e1] + i1;
    perm[p0] = t; pgate[p0] = topk_g[2 * t];
    perm[p1] = t; pgate[p1] = topk_g[2 * t + 1];
}

// ---------------------------------------------------------------------------
// Expert FFN v5: XCD-affinity persistent grid (2048 blocks; group q=bid&7).
// 4 waves; wave w owns N-quarter, both 16-row m-tiles. B staged via
// global_load_lds into a per-wave 4 x 2KB ring: chunk = 2 B-frags = 4 MFMAs,
// prefetch lead = 4 chunks (~8 loads in flight, vmcnt(6) steady wait) to
// cover L3-class (~600cyc) latency that R4's 2-deep ring could not.
// MFMA 16x16x32 bf16 layouts: A[m=lane&15][k=(lane>>4)*8+j];
// C/D col=lane&15, row=(lane>>4)*4+reg.
__global__ __launch_bounds__(256, 2) void expert_ffn(const float* __restrict__ x,
                                                     const uint4* __restrict__ W1f,
                                                     const uint4* __restrict__ W2f,
                                                     const float* __restrict__ b1,
                                                     const float* __restrict__ b2,
                                                     const int* __restrict__ cnt,
                                                     const int* __restrict__ offs,
                                                     const int* __restrict__ gOffs,
                                                     const int* __restrict__ perm,
                                                     const float* __restrict__ pgate,
                                                     float* __restrict__ out) {
    __shared__ unsigned short Hs[TM][DHID + 8];   // 33,280 B
    __shared__ uint4 Bst[4][4][128];              // 4 waves x 4-ring x 2KB = 32 KB
    __shared__ float bias1s[DHID];                // 2 KB
    __shared__ float bias2s[DOUT];                // 1 KB
    __shared__ int toks[TM];
    __shared__ float gs[TM];
    __shared__ int sOff[9];

    int tid = threadIdx.x;
    int q = blockIdx.x & 7, slot = blockIdx.x >> 3;
    if (tid < 9) sOff[tid] = gOffs[q * 9 + tid];
    __syncthreads();
    int L = sOff[8];
    int w = tid >> 6, lane = tid & 63, quad = lane >> 4, lr = lane & 15;

    for (int s = slot; s < L; s += 256) {
        // expert within group (8 experts, zero-width ranges for empty)
        int j = 0;
#pragma unroll
        for (int jj = 1; jj < 8; ++jj) j += (sOff[jj] <= s) ? 1 : 0;
        int e = q + 8 * j;
        int ne = cnt[e];
        int tile0 = (s - sOff[j]) * TM;

        __syncthreads();   // prev iteration fully done with toks/gs/bias/Hs
        if (tid < TM) {
            int idx = tile0 + tid;
            if (idx < ne) { int p = offs[e] + idx; toks[tid] = perm[p]; gs[tid] = pgate[p]; }
            else          { toks[tid] = 0; gs[tid] = 0.0f; }   // gate 0 -> no-op
        }
        if (tid < 128)
            *(float4*)&bias1s[tid * 4] = *(const float4*)(b1 + (size_t)e * DHID + tid * 4);
        else if (tid < 192)
            *(float4*)&bias2s[(tid - 128) * 4] = *(const float4*)(b2 + (size_t)e * DOUT + (tid - 128) * 4);
        __syncthreads();

        // wave-private weight bases (per-lane 16B slot)
        const uint4* W1base = W1f + (size_t)e * 16384 + (size_t)(w * 8) * 512 + lane;
        const uint4* W2base = W2f + (size_t)e * 16384 + (size_t)(w * 4) * 1024 + lane;

        // layer1 chunk c: n-tile i=c>>2 (nt=w*8+i), k-pair p=c&3 (kt=2p,2p+1)
        auto stage1 = [&](int c) {
            const uint4* g = W1base + (size_t)(c >> 2) * 512 + (size_t)(c & 3) * 128;
            uint4* d = &Bst[w][c & 3][0];
            async_copy16(g, d);
            async_copy16(g + 64, d + 64);
        };
        // layer2 chunk c: n-tile i=c>>3 (ng=w*4+i), k-pair p=c&7 (kt=2p,2p+1)
        auto stage2 = [&](int c) {
            const uint4* g = W2base + (size_t)(c >> 3) * 1024 + (size_t)(c & 7) * 128;
            uint4* d = &Bst[w][c & 3][0];
            async_copy16(g, d);
            async_copy16(g + 64, d + 64);
        };

        stage1(0); stage1(1); stage1(2); stage1(3);   // 8 loads in flight

        // ---- x A-frags direct from global (fp32 -> bf16) ----
        short8 a1[2][8];
#pragma unroll
        for (int mt = 0; mt < 2; ++mt) {
            const float* xr = x + (size_t)toks[mt * 16 + lr] * DIN + quad * 8;
#pragma unroll
            for (int kk = 0; kk < 8; ++kk) {
                float4 u = *(const float4*)(xr + kk * 32);
                float4 v = *(const float4*)(xr + kk * 32 + 4);
                short8 t;
                t[0] = (short)f2bf(u.x); t[1] = (short)f2bf(u.y);
                t[2] = (short)f2bf(u.z); t[3] = (short)f2bf(u.w);
                t[4] = (short)f2bf(v.x); t[5] = (short)f2bf(v.y);
                t[6] = (short)f2bf(v.z); t[7] = (short)f2bf(v.w);
                a1[mt][kk] = t;
            }
        }

        // ---- layer 1 pipeline: 32 chunks ----
        f32x4 acc0 = {0.f,0.f,0.f,0.f}, acc1 = {0.f,0.f,0.f,0.f};
#pragma unroll
        for (int c = 0; c < 32; ++c) {
            int p = c & 3;
            if (p == 0) { acc0 = (f32x4){0.f,0.f,0.f,0.f}; acc1 = (f32x4){0.f,0.f,0.f,0.f}; }
            if (c < 29)      __builtin_amdgcn_s_waitcnt(0x0F76);   // vmcnt(6)
            else if (c == 29) __builtin_amdgcn_s_waitcnt(0x0F74);  // vmcnt(4)
            else if (c == 30) __builtin_amdgcn_s_waitcnt(0x0F72);  // vmcnt(2)
            else              __builtin_amdgcn_s_waitcnt(0x0F70);  // vmcnt(0)
            const uint4* bb = &Bst[w][c & 3][0];
            short8 b0 = *(const short8*)&bb[lane];
            short8 b1v = *(const short8*)&bb[64 + lane];
            int kk = 2 * p;
            acc0 = __builtin_amdgcn_mfma_f32_16x16x32_bf16(a1[0][kk], b0, acc0, 0, 0, 0);
            acc1 = __builtin_amdgcn_mfma_f32_16x16x32_bf16(a1[1][kk], b0, acc1, 0, 0, 0);
            acc0 = __builtin_amdgcn_mfma_f32_16x16x32_bf16(a1[0][kk + 1], b1v, acc0, 0, 0, 0);
            acc1 = __builtin_amdgcn_mfma_f32_16x16x32_bf16(a1[1][kk + 1], b1v, acc1, 0, 0, 0);
            if (c + 4 < 32) stage1(c + 4);   // issued after MFMAs consumed chunk c
            if (p == 3) {
                int n = w * 128 + (c >> 2) * 16;
                float bias = bias1s[n + lr];
#pragma unroll
                for (int r = 0; r < 4; ++r) {
                    Hs[quad * 4 + r][n + lr]      = f2bf(fmaxf(acc0[r] + bias, 0.0f));
                    Hs[16 + quad * 4 + r][n + lr] = f2bf(fmaxf(acc1[r] + bias, 0.0f));
                }
            }
        }

        stage2(0); stage2(1); stage2(2); stage2(3);
        __syncthreads();   // H complete (drains DMAs once; data preserved in LDS)

        // ---- layer 2 pipeline: 32 chunks ----
        f32x4 acc2[4][2];
#pragma unroll
        for (int i = 0; i < 4; ++i)
#pragma unroll
            for (int mt = 0; mt < 2; ++mt) acc2[i][mt] = (f32x4){0.f,0.f,0.f,0.f};
#pragma unroll
        for (int c = 0; c < 32; ++c) {
            int i2 = c >> 3, p = c & 7;
            if (c < 29)      __builtin_amdgcn_s_waitcnt(0x0F76);
            else if (c == 29) __builtin_amdgcn_s_waitcnt(0x0F74);
            else if (c == 30) __builtin_amdgcn_s_waitcnt(0x0F72);
            else              __builtin_amdgcn_s_waitcnt(0x0F70);
            const uint4* bb = &Bst[w][c & 3][0];
            short8 b0 = *(const short8*)&bb[lane];
            short8 b1v = *(const short8*)&bb[64 + lane];
            int kt = 2 * p;
            short8 a00 = *(const short8*)&Hs[lr][kt * 32 + quad * 8];
            short8 a01 = *(const short8*)&Hs[16 + lr][kt * 32 + quad * 8];
            short8 a10 = *(const short8*)&Hs[lr][(kt + 1) * 32 + quad * 8];
            short8 a11 = *(const short8*)&Hs[16 + lr][(kt + 1) * 32 + quad * 8];
            acc2[i2][0] = __builtin_amdgcn_mfma_f32_16x16x32_bf16(a00, b0, acc2[i2][0], 0, 0, 0);
            acc2[i2][1] = __builtin_amdgcn_mfma_f32_16x16x32_bf16(a01, b0, acc2[i2][1], 0, 0, 0);
            acc2[i2][0] = __builtin_amdgcn_mfma_f32_16x16x32_bf16(a10, b1v, acc2[i2][0], 0, 0, 0);
            acc2[i2][1] = __builtin_amdgcn_mfma_f32_16x16x32_bf16(a11, b1v, acc2[i2][1], 0, 0, 0);
            if (c + 4 < 32) stage2(c + 4);
        }

        // ---- deferred epilogue: out[tok] += gate * (y + b2) ----
#pragma unroll
        for (int i = 0; i < 4; ++i) {
            int n = (w * 4 + i) * 16;
            float bias = bias2s[n + lr];
#pragma unroll
            for (int mt = 0; mt < 2; ++mt)
#pragma unroll
                for (int r = 0; r < 4; ++r) {
                    int m = mt * 16 + quad * 4 + r;
                    atomicAdd(&out[(size_t)toks[m] * DOUT + n + lr],
                              gs[m] * (acc2[i][mt][r] + bias));
                }
        }
    }
}

// ---------------------------------------------------------------------------
extern "C" void kernel_launch(void* const* d_in, const int* in_sizes, int n_in,
                              void* d_out, int out_size, void* d_ws, size_t ws_size,
                              hipStream_t stream) {
    (void)in_sizes; (void)n_in; (void)ws_size; (void)out_size;   // ws >= ~34.6 MB
    const float* x  = (const float*)d_in[0];
    const float* Wr = (const float*)d_in[1];
    const float* br = (const float*)d_in[2];
    const float* W1 = (const float*)d_in[3];
    const float* b1 = (const float*)d_in[4];
    const float* W2 = (const float*)d_in[5];
    const float* b2 = (const float*)d_in[6];
    float* out = (float*)d_out;
    char* ws = (char*)d_ws;

    uint4* W1f    = (uint4*)(ws + OFF_W1F);
    uint4* W2f    = (uint4*)(ws + OFF_W2F);
    int*   cnt    = (int*)(ws + OFF_CNT);
    int*   cursor = (int*)(ws + OFF_CUR);
    int*   offs   = (int*)(ws + OFF_OFFS);
    int*   gOffs  = (int*)(ws + OFF_GOFF);
    int*   topk_e = (int*)(ws + OFF_TOPKE);
    float* topk_g = (float*)(ws + OFF_TOPKG);
    int*   perm   = (int*)(ws + OFF_PERM);
    float* pgate  = (float*)(ws + OFF_PGATE);

    hipMemsetAsync(ws + OFF_CNT, 0, 512, stream);   // cnt + cursor

    router_prep<<<ROUTER_BLOCKS + PREP_BLOCKS + OUTZ_BLOCKS, 256, 0, stream>>>(
        x, Wr, br, W1, W2, W1f, W2f, topk_e, topk_g, cnt, (float4*)out);
    scatter_kernel<<<T_TOK / 256, 256, 0, stream>>>(topk_e, topk_g, cnt, cursor,
                                                    perm, pgate, offs, gOffs);
    expert_ffn<<<FFN_BLOCKS, 256, 0, stream>>>(x, W1f, W2f, b1, b2, cnt, offs, gOffs,
                                               perm, pgate, out);
}